// Round 11
// baseline (1640.864 us; speedup 1.0000x reference)
//
#include <hip/hip_runtime.h>
#include <cstddef>
#include <cstdint>

// SNN: 4x (Linear + LIF). bf16 MFMA via EXACT 3-term splitting, scale-
// segregated accumulation (per-acc MFMA chain order identical to R10 ->
// bit-identical numerics). gemm_bd<NB,HM>: BM=128, BN=128, BK=64, 4 waves,
// 2 blocks/CU (m114 overlap). B fragments read DIRECTLY from global (plain
// row-major weights; frag = 16 rows x 64B full cache lines, L2-served with
// column-major XCD-chunked swizzle -> <=3MB B per XCD L2). Only A in LDS
// (mode-1 swizzle, dbuf, 32KB). One vmcnt(4NB+2)+barrier per phase.
// L3 keeps gemm_seg (mode-0 operands).

#define BETA 0.95f

static constexpr int B_ = 128;
static constexpr int T_ = 64;
static constexpr int M_ = B_ * T_;       // 8192 rows
static constexpr int NOUT = 128;

typedef __bf16 bf16x8 __attribute__((ext_vector_type(8)));
typedef float f32x4 __attribute__((ext_vector_type(4)));
typedef ushort u16x8 __attribute__((ext_vector_type(8)));

__device__ __forceinline__ ushort f32_bf16_rne(float f) {
  uint32_t u = __float_as_uint(f);
  uint32_t r = u + 0x7FFFu + ((u >> 16) & 1u);
  return (ushort)(r >> 16);
}
__device__ __forceinline__ float bf16_f32(ushort h) {
  return __uint_as_float(((uint32_t)h) << 16);
}

// ---------------------------------------------------------------------------
// fp32 -> 3 bf16 exact split.
// mode 0: stored slot = slot ^ (row&7)               (gemm_seg operands)
// mode 1: stored slot = (slot&4)|((slot&3)^((row>>1)&3))  (gemm_bd A operand)
// mode 2: plain (no permute)                          (gemm_bd B operand)
// ---------------------------------------------------------------------------
__global__ __launch_bounds__(256) void split3_swz(
    const float* __restrict__ S, ushort* __restrict__ o1,
    ushort* __restrict__ o2, ushort* __restrict__ o3,
    int K, int nslots, int mode)
{
  int g = blockIdx.x * 256 + threadIdx.x;
  if (g >= nslots) return;
  int spr = K >> 3;
  int row = g / spr;
  int sl = g - row * spr;
  int kb = sl >> 3;
  int slot = sl & 7;
  int pslot = (mode == 1) ? ((slot & 4) | ((slot & 3) ^ ((row >> 1) & 3)))
            : (mode == 0) ? (slot ^ (row & 7))
                          : slot;
  const float* src = S + (size_t)row * K + (kb << 6) + (slot << 3);
  size_t dst = (size_t)row * K + (kb << 6) + (pslot << 3);
  u16x8 v1, v2, v3;
#pragma unroll
  for (int i = 0; i < 8; ++i) {
    float f = src[i];
    ushort h1 = f32_bf16_rne(f);
    float r = f - bf16_f32(h1);
    ushort h2 = f32_bf16_rne(r);
    float r2 = r - bf16_f32(h2);
    ushort h3 = f32_bf16_rne(r2);
    v1[i] = h1; v2[i] = h2; v3[i] = h3;
  }
  *reinterpret_cast<u16x8*>(o1 + dst) = v1;
  *reinterpret_cast<u16x8*>(o2 + dst) = v2;
  *reinterpret_cast<u16x8*>(o3 + dst) = v3;
}

// ---------------------------------------------------------------------------
// gemm_seg (L3 only): 128x128 tile, BK=64, 4 waves, mode-0 swizzle.
// ---------------------------------------------------------------------------
__global__ __launch_bounds__(256) void gemm_seg(
    const ushort* __restrict__ A0, const ushort* __restrict__ A1,
    const ushort* __restrict__ A2,
    const ushort* __restrict__ B0, const ushort* __restrict__ B1,
    const ushort* __restrict__ B2,
    int P, int apack, int bpack, int K, int N, int accum,
    float* __restrict__ C)
{
  __shared__ ushort As[128 * 64];
  __shared__ ushort Bs[128 * 64];

  const int tid = threadIdx.x;
  const int lane = tid & 63;
  const int wid = tid >> 6;
  const int wr = wid >> 1, wc = wid & 1;
  const int lane15 = lane & 15;
  const int lhi = lane >> 4;
  const int rswz = lane15 & 7;
  const int lrow = lane >> 3, lslot = lane & 7;

  int nwg = gridDim.x * gridDim.y;
  int bid = blockIdx.y * gridDim.x + blockIdx.x;
  int cpx = nwg >> 3;
  int sw = (bid & 7) * cpx + (bid >> 3);
  int bx = sw % gridDim.x, by = sw / gridDim.x;
  const int bm = by * 128, bn = bx * 128;

  f32x4 acc[4][4];
#pragma unroll
  for (int i = 0; i < 4; ++i)
#pragma unroll
    for (int j = 0; j < 4; ++j)
      acc[i][j] = (f32x4){0.f, 0.f, 0.f, 0.f};

  const bool isA = (wid < 2);
  ushort* lbase = isA ? As : Bs;
  const int rowbase0 = isA ? bm : bn;
  const int chunk0 = (wid & 1) * 8;

  for (int p = 0; p < P; ++p) {
    int ai = (apack >> (2 * p)) & 3;
    int bi = (bpack >> (2 * p)) & 3;
    const ushort* Ap = ai == 0 ? A0 : (ai == 1 ? A1 : A2);
    const ushort* Bp = bi == 0 ? B0 : (bi == 1 ? B1 : B2);
    const ushort* gsrc = isA ? Ap : Bp;
    for (int k0 = 0; k0 < K; k0 += 64) {
      __syncthreads();
#pragma unroll
      for (int c = 0; c < 8; ++c) {
        int chunk = chunk0 + c;
        int row = chunk * 8 + lrow;
        const ushort* g = gsrc + (size_t)(rowbase0 + row) * K + k0 + (lslot << 3);
        __builtin_amdgcn_global_load_lds(
            (const __attribute__((address_space(1))) void*)(g),
            (__attribute__((address_space(3))) void*)(lbase + chunk * 512),
            16, 0, 0);
      }
      __syncthreads();
#pragma unroll
      for (int kk = 0; kk < 2; ++kk) {
        int sp = ((kk << 2) | lhi) ^ rswz;
        bf16x8 af[4], bg[4];
#pragma unroll
        for (int i = 0; i < 4; ++i)
          af[i] = *(const bf16x8*)(As + (wr * 64 + i * 16 + lane15) * 64 + sp * 8);
#pragma unroll
        for (int j = 0; j < 4; ++j)
          bg[j] = *(const bf16x8*)(Bs + (wc * 64 + j * 16 + lane15) * 64 + sp * 8);
#pragma unroll
        for (int i = 0; i < 4; ++i)
#pragma unroll
          for (int j = 0; j < 4; ++j)
            acc[i][j] = __builtin_amdgcn_mfma_f32_16x16x32_bf16(
                af[i], bg[j], acc[i][j], 0, 0, 0);
      }
    }
  }

#pragma unroll
  for (int j = 0; j < 4; ++j) {
    int col = bn + wc * 64 + j * 16 + lane15;
#pragma unroll
    for (int i = 0; i < 4; ++i) {
      f32x4 v = acc[i][j];
      int r0 = bm + wr * 64 + i * 16 + lhi * 4;
      if (accum) {
#pragma unroll
        for (int r = 0; r < 4; ++r) {
          size_t idx = (size_t)(r0 + r) * N + col;
          C[idx] = C[idx] + v[r];
        }
      } else {
#pragma unroll
        for (int r = 0; r < 4; ++r)
          C[(size_t)(r0 + r) * N + col] = v[r];
      }
    }
  }
}

// ---------------------------------------------------------------------------
// gemm_bd<NB, HM>: BM=128, BN=128, BK=64 (K=2048, NT=32), 4 waves (2Mx2N,
// per-wave 64x64), 2 blocks/CU. A in LDS (mode-1 swizzled src, [2d][2h]
// [128][32], 32KB); B read directly global->regs (plain layout; per frag
// 16 rows x 64B = full lines). Per phase (t,h): issue B(t,h) 4*NB loads;
// stage A for phase p+2 (2 gload_lds, dest slot d^1 always); vmcnt(4NB+2)
// (drains phase p-1's A-stage -> slot read at p+1 ready); barrier; af
// ds_reads; MFMA (compiler waits bf regs). Tail stages clamp src, dest d^1
// (dead slot). accM = seg0 main chain (HM), accC = corr chain -> identical
// order to R10.
// ---------------------------------------------------------------------------
template<int NB, bool HM>
__global__ __launch_bounds__(256, 2) void gemm_bd(
    const ushort* __restrict__ A,
    const ushort* __restrict__ Bp0, const ushort* __restrict__ Bp1,
    const ushort* __restrict__ Bp2,
    int N, float* __restrict__ C)
{
  __shared__ __align__(16) ushort lds[2 * 2 * 128 * 32];  // 32 KB

  const int tid = threadIdx.x;     // 0..255
  const int lane = tid & 63;
  const int wid = tid >> 6;        // 0..3
  const int wm = wid >> 1;         // 0..1 (64-row strip)
  const int wn = wid & 1;          // 0..1 (64-col strip)
  const int lane15 = lane & 15;
  const int lhi = lane >> 4;
  const int s2 = lhi ^ ((lane15 >> 1) & 3);   // mode-1 A read granule

  // column-major XCD-chunked swizzle: chunk spans few bx -> B fits XCD L2
  int gx = gridDim.x, gy = gridDim.y;
  int nwg = gx * gy;
  int bid = blockIdx.y * gx + blockIdx.x;
  int cpx = nwg >> 3;
  int sw = (bid & 7) * cpx + (bid >> 3);
  int bx = sw / gy;
  int by = sw - bx * gy;
  const int bm = by * 128, bn = bx * 128;

  // A staging: 512 granules of 16B; thread covers G = tid, tid+256
  auto stageA = [&](int tsrc, int h, int dd) {
    ushort* dst = lds + (dd * 2 + h) * 4096;
    const int k0 = tsrc * 64 + h * 32;
#pragma unroll
    for (int l = 0; l < 2; ++l) {
      int G = tid + l * 256;
      int row = G >> 2, gc = G & 3;
      __builtin_amdgcn_global_load_lds(
          (const __attribute__((address_space(1))) void*)(A + (size_t)(bm + row) * 2048 + k0 + gc * 8),
          (__attribute__((address_space(3))) void*)(dst + G * 8), 16, 0, 0);
    }
  };

  // per-lane B base addresses (plain layout, col stride 2048)
  const int colb = bn + wn * 64 + lane15;
  const ushort* bb0 = Bp0 + (size_t)colb * 2048 + lhi * 8;
  const ushort* bb1 = Bp1 + (size_t)colb * 2048 + lhi * 8;
  const ushort* bb2 = Bp2 + (size_t)colb * 2048 + lhi * 8;

  f32x4 accM[4][4], accC[4][4];
#pragma unroll
  for (int i = 0; i < 4; ++i)
#pragma unroll
    for (int j = 0; j < 4; ++j) {
      accM[i][j] = (f32x4){0.f, 0.f, 0.f, 0.f};
      accC[i][j] = (f32x4){0.f, 0.f, 0.f, 0.f};
    }

  const int NT = 32;

  // prologue: stage both halves of tile 0; drain; barrier
  stageA(0, 0, 0);
  stageA(0, 1, 0);
  asm volatile("s_waitcnt vmcnt(0)" ::: "memory");
  __builtin_amdgcn_s_barrier();

  for (int t = 0; t < NT; ++t) {
    const int d = t & 1;
    const int tn = (t + 1 < NT) ? (t + 1) : (NT - 1);
#pragma unroll
    for (int h = 0; h < 2; ++h) {
      // B loads for THIS phase (before barrier; latency covered by sibling
      // block + barrier/ds_read gap; compiler inserts the bf vmcnt)
      bf16x8 bf[NB * 4];
      const int k0 = t * 64 + h * 32;
#pragma unroll
      for (int s = 0; s < NB; ++s) {
        const ushort* bs = (s == 0) ? bb0 : ((s == 1) ? bb1 : bb2);
#pragma unroll
        for (int j = 0; j < 4; ++j)
          bf[s * 4 + j] = *(const bf16x8*)(bs + (size_t)(j * 16) * 2048 + k0);
      }
      // A stage for phase p+2 (tile t+1, same h); dest slot d^1 (dead slot)
      stageA(tn, h, d ^ 1);

      if constexpr (NB == 3) asm volatile("s_waitcnt vmcnt(14)" ::: "memory");
      if constexpr (NB == 2) asm volatile("s_waitcnt vmcnt(10)" ::: "memory");
      if constexpr (NB == 1) asm volatile("s_waitcnt vmcnt(6)" ::: "memory");
      __builtin_amdgcn_s_barrier();

      bf16x8 af[4];
      const ushort* Ab = lds + (d * 2 + h) * 4096;
#pragma unroll
      for (int i = 0; i < 4; ++i)
        af[i] = *(const bf16x8*)(Ab + (wm * 64 + i * 16 + lane15) * 32 + s2 * 8);

      __builtin_amdgcn_s_setprio(1);
#pragma unroll
      for (int s = 0; s < NB; ++s) {
        if (HM && s == 0) {
#pragma unroll
          for (int i = 0; i < 4; ++i)
#pragma unroll
            for (int j = 0; j < 4; ++j)
              accM[i][j] = __builtin_amdgcn_mfma_f32_16x16x32_bf16(af[i], bf[s * 4 + j], accM[i][j], 0, 0, 0);
        } else {
#pragma unroll
          for (int i = 0; i < 4; ++i)
#pragma unroll
            for (int j = 0; j < 4; ++j)
              accC[i][j] = __builtin_amdgcn_mfma_f32_16x16x32_bf16(af[i], bf[s * 4 + j], accC[i][j], 0, 0, 0);
        }
      }
      __builtin_amdgcn_s_setprio(0);
    }
  }
  asm volatile("s_waitcnt vmcnt(0)" ::: "memory");  // drain tail dummies

  // epilogue: C/D layout col = lane&15, row = (lane>>4)*4 + reg
#pragma unroll
  for (int i = 0; i < 4; ++i) {
    int r0 = bm + wm * 64 + i * 16 + lhi * 4;
#pragma unroll
    for (int j = 0; j < 4; ++j) {
      int col = bn + wn * 64 + j * 16 + lane15;
      f32x4 vc = accC[i][j];
      if (HM) {
        f32x4 vm = accM[i][j];
#pragma unroll
        for (int r = 0; r < 4; ++r)
          C[(size_t)(r0 + r) * N + col] = vm[r] + vc[r];
      } else {
#pragma unroll
        for (int r = 0; r < 4; ++r) {
          size_t idx = (size_t)(r0 + r) * N + col;
          C[idx] = C[idx] + vc[r];
        }
      }
    }
  }
}

// ---------------------------------------------------------------------------
// LIF scan: cur = buf + bias (single rounding); spikes bf16 {0,1} in
// swizzled layout (mode 1 for gemm_bd A; mode 0 for gemm_seg).
// ---------------------------------------------------------------------------
__global__ __launch_bounds__(256) void lif_spk_swz(
    const float* __restrict__ cur, const float* __restrict__ bias,
    ushort* __restrict__ spk, int N, int total, int mode)
{
  int g = blockIdx.x * 256 + threadIdx.x;
  if (g >= total) return;
  int b = g / N, n = g - b * N;
  int nb = n >> 6;
  int slot = (n >> 3) & 7;
  int nlow = n & 7;
  float bv = bias[n];
  float mem = 0.f;
  for (int t = 0; t < T_; ++t) {
    int m = b * T_ + t;
    float c = __fadd_rn(cur[(size_t)m * N + n], bv);
    float reset = ((mem - 1.0f) > 0.0f) ? 1.0f : 0.0f;
    mem = __fmul_rn(BETA, mem);
    mem = __fadd_rn(mem, c);
    mem = __fadd_rn(mem, -reset);
    ushort sv = ((mem - 1.0f) > 0.0f) ? (ushort)0x3F80 : (ushort)0;
    int ps = mode ? ((slot & 4) | ((slot & 3) ^ ((m >> 1) & 3)))
                  : (slot ^ (m & 7));
    spk[(size_t)m * N + (nb << 6) + (ps << 3) + nlow] = sv;
  }
}

__global__ __launch_bounds__(256) void lif_final(
    const float* __restrict__ cur_in, const float* __restrict__ bias,
    float* __restrict__ spk_out, float* __restrict__ mem_out, int N, int total)
{
  int g = blockIdx.x * 256 + threadIdx.x;
  if (g >= total) return;
  int b = g / N, n = g - b * N;
  size_t base = (size_t)b * T_ * N + n;
  float bv = bias[n];
  float mem = 0.f;
  for (int t = 0; t < T_; ++t) {
    size_t idx = base + (size_t)t * N;
    float c = __fadd_rn(cur_in[idx], bv);
    float reset = ((mem - 1.0f) > 0.0f) ? 1.0f : 0.0f;
    mem = __fmul_rn(BETA, mem);
    mem = __fadd_rn(mem, c);
    mem = __fadd_rn(mem, -reset);
    spk_out[idx] = ((mem - 1.0f) > 0.0f) ? 1.0f : 0.0f;
    mem_out[idx] = mem;
  }
}

extern "C" void kernel_launch(void* const* d_in, const int* in_sizes, int n_in,
                              void* d_out, int out_size, void* d_ws, size_t ws_size,
                              hipStream_t stream)
{
  const float* x  = (const float*)d_in[0];
  const float* W0 = (const float*)d_in[1];
  const float* b0 = (const float*)d_in[2];
  const float* W1 = (const float*)d_in[3];
  const float* b1 = (const float*)d_in[4];
  const float* W2 = (const float*)d_in[5];
  const float* b2 = (const float*)d_in[6];
  const float* W3 = (const float*)d_in[7];
  const float* b3 = (const float*)d_in[8];
  float* out = (float*)d_out;

  char* ws = (char*)d_ws;
  size_t off = 0;
  auto take = [&](size_t bytes) -> char* {
    char* p = ws + off;
    off += (bytes + 255) & ~(size_t)255;
    return p;
  };

  ushort* w0s[3], *w1s[3], *w2s[3], *w3s[3], *xs[3];
  for (int i = 0; i < 3; ++i) w0s[i] = (ushort*)take((size_t)2048 * 2048 * 2);
  for (int i = 0; i < 3; ++i) w1s[i] = (ushort*)take((size_t)2048 * 2048 * 2);
  for (int i = 0; i < 3; ++i) w2s[i] = (ushort*)take((size_t)1024 * 2048 * 2);
  for (int i = 0; i < 3; ++i) w3s[i] = (ushort*)take((size_t)128 * 1024 * 2);
  for (int i = 0; i < 3; ++i) xs[i]  = (ushort*)take((size_t)M_ * 2048 * 2);
  float* cur = (float*)take((size_t)M_ * 2048 * 4);
  // spike buffers alias the x-split region (dead after L0 GEMMs)
  ushort* s0 = xs[0];
  ushort* s1 = xs[1];
  ushort* s2 = xs[2];

  dim3 blk(256);

  // --- splits: x mode 1 (A); W0/W1/W2 mode 2 (plain, B-direct); W3 mode 0 ---
  {
    int ns = 2048 * 2048 / 8;
    split3_swz<<<(ns + 255) / 256, blk, 0, stream>>>(W0, w0s[0], w0s[1], w0s[2], 2048, ns, 2);
    split3_swz<<<(ns + 255) / 256, blk, 0, stream>>>(W1, w1s[0], w1s[1], w1s[2], 2048, ns, 2);
    ns = 1024 * 2048 / 8;
    split3_swz<<<(ns + 255) / 256, blk, 0, stream>>>(W2, w2s[0], w2s[1], w2s[2], 2048, ns, 2);
    ns = 128 * 1024 / 8;
    split3_swz<<<(ns + 255) / 256, blk, 0, stream>>>(W3, w3s[0], w3s[1], w3s[2], 1024, ns, 0);
    ns = M_ * 2048 / 8;
    split3_swz<<<(ns + 255) / 256, blk, 0, stream>>>(x, xs[0], xs[1], xs[2], 2048, ns, 1);
  }

  // --- L0: fused by A-segment (grid 16x64 = 1024 blocks = 2/CU) ---
  {
    dim3 grid(2048 / 128, M_ / 128);
    gemm_bd<3, true><<<grid, blk, 0, stream>>>(xs[0], w0s[0], w0s[1], w0s[2], 2048, cur);
    gemm_bd<2, false><<<grid, blk, 0, stream>>>(xs[1], w0s[0], w0s[1], w0s[1], 2048, cur);
    gemm_bd<1, false><<<grid, blk, 0, stream>>>(xs[2], w0s[0], w0s[0], w0s[0], 2048, cur);
    lif_spk_swz<<<(B_ * 2048) / 256, blk, 0, stream>>>(cur, b0, s0, 2048, B_ * 2048, 1);
  }
  // --- L1: one fused launch ---
  {
    dim3 grid(2048 / 128, M_ / 128);
    gemm_bd<3, true><<<grid, blk, 0, stream>>>(s0, w1s[0], w1s[1], w1s[2], 2048, cur);
    lif_spk_swz<<<(B_ * 2048) / 256, blk, 0, stream>>>(cur, b1, s1, 2048, B_ * 2048, 1);
  }
  // --- L2: one fused launch (grid 8x64 = 512 blocks = 2/CU) ---
  {
    dim3 grid(1024 / 128, M_ / 128);
    gemm_bd<3, true><<<grid, blk, 0, stream>>>(s1, w2s[0], w2s[1], w2s[2], 1024, cur);
    lif_spk_swz<<<(B_ * 1024) / 256, blk, 0, stream>>>(cur, b2, s2, 1024, B_ * 1024, 0);
  }
  // --- L3 (gemm_seg, mode-0) + final LIF ---
  {
    dim3 grid(128 / 128, M_ / 128);
    gemm_seg<<<grid, blk, 0, stream>>>(s2, s2, s2, w3s[0], w3s[1], w3s[2],
                                       1, 0, 0, 1024, 128, 0, cur);
    gemm_seg<<<grid, blk, 0, stream>>>(s2, s2, s2, w3s[0], w3s[1], w3s[2],
                                       2, 0, 1 | (2 << 2), 1024, 128, 1, cur);
    float* spk3 = out;
    float* mem3 = out + (size_t)M_ * NOUT;
    lif_final<<<(B_ * NOUT) / 256, blk, 0, stream>>>(cur, b3, spk3, mem3, NOUT, B_ * NOUT);
  }
}

// Round 12
// 886.292 us; speedup vs baseline: 1.8514x; 1.8514x over previous
//
#include <hip/hip_runtime.h>
#include <cstddef>
#include <cstdint>

// SNN: 4x (Linear + LIF). bf16 MFMA via EXACT 3-term splitting, scale-
// segregated dual accumulators (accM bit-identical main chain; accC corr).
// gemm_lif: whole layer in ONE launch. BM=256 x BN=128, BK=64, 8 waves
// (4Mx2N), LDS 160KB (A 2dbuf x 2half x [256][32]; B 2x2x3x[128][32]).
// One stage(10 loads)+vmcnt(10)+barrier+MFMA+barrier per K-tile.
// Epilogue: acc -> LDS [128][130] f32 (2 batches/group), in-LDS LIF scan,
// swizzled bf16 spike store. No cur round-trip for L0-L2.
// L3 (tiny) keeps gemm_seg + lif_final (mode-0 operands, 4MB cur).

#define BETA 0.95f

static constexpr int B_ = 128;
static constexpr int T_ = 64;
static constexpr int M_ = B_ * T_;       // 8192 rows
static constexpr int NOUT = 128;

typedef __bf16 bf16x8 __attribute__((ext_vector_type(8)));
typedef float f32x4 __attribute__((ext_vector_type(4)));
typedef ushort u16x8 __attribute__((ext_vector_type(8)));

struct PassArgs {
  const ushort* A[3];
  const ushort* B[3][3];
};

__device__ __forceinline__ ushort f32_bf16_rne(float f) {
  uint32_t u = __float_as_uint(f);
  uint32_t r = u + 0x7FFFu + ((u >> 16) & 1u);
  return (ushort)(r >> 16);
}
__device__ __forceinline__ float bf16_f32(ushort h) {
  return __uint_as_float(((uint32_t)h) << 16);
}

// ---------------------------------------------------------------------------
// fp32 -> 3 bf16 exact split at swizzled slot positions.
// mode 0 (gemm_seg): stored slot = slot ^ (row&7)
// mode 1 (gemm_lif): stored slot = (slot&4)|((slot&3)^((row>>1)&3))
// ---------------------------------------------------------------------------
__global__ __launch_bounds__(256) void split3_swz(
    const float* __restrict__ S, ushort* __restrict__ o1,
    ushort* __restrict__ o2, ushort* __restrict__ o3,
    int K, int nslots, int mode)
{
  int g = blockIdx.x * 256 + threadIdx.x;
  if (g >= nslots) return;
  int spr = K >> 3;
  int row = g / spr;
  int sl = g - row * spr;
  int kb = sl >> 3;
  int slot = sl & 7;
  int pslot = mode ? ((slot & 4) | ((slot & 3) ^ ((row >> 1) & 3)))
                   : (slot ^ (row & 7));
  const float* src = S + (size_t)row * K + (kb << 6) + (slot << 3);
  size_t dst = (size_t)row * K + (kb << 6) + (pslot << 3);
  u16x8 v1, v2, v3;
#pragma unroll
  for (int i = 0; i < 8; ++i) {
    float f = src[i];
    ushort h1 = f32_bf16_rne(f);
    float r = f - bf16_f32(h1);
    ushort h2 = f32_bf16_rne(r);
    float r2 = r - bf16_f32(h2);
    ushort h3 = f32_bf16_rne(r2);
    v1[i] = h1; v2[i] = h2; v3[i] = h3;
  }
  *reinterpret_cast<u16x8*>(o1 + dst) = v1;
  *reinterpret_cast<u16x8*>(o2 + dst) = v2;
  *reinterpret_cast<u16x8*>(o3 + dst) = v3;
}

// ---------------------------------------------------------------------------
// gemm_seg (L3 only): 128x128 tile, BK=64, 4 waves, mode-0 swizzle.
// ---------------------------------------------------------------------------
__global__ __launch_bounds__(256) void gemm_seg(
    const ushort* __restrict__ A0, const ushort* __restrict__ A1,
    const ushort* __restrict__ A2,
    const ushort* __restrict__ B0, const ushort* __restrict__ B1,
    const ushort* __restrict__ B2,
    int P, int apack, int bpack, int K, int N, int accum,
    float* __restrict__ C)
{
  __shared__ ushort As[128 * 64];
  __shared__ ushort Bs[128 * 64];

  const int tid = threadIdx.x;
  const int lane = tid & 63;
  const int wid = tid >> 6;
  const int wr = wid >> 1, wc = wid & 1;
  const int lane15 = lane & 15;
  const int lhi = lane >> 4;
  const int rswz = lane15 & 7;
  const int lrow = lane >> 3, lslot = lane & 7;

  int nwg = gridDim.x * gridDim.y;
  int bid = blockIdx.y * gridDim.x + blockIdx.x;
  int cpx = nwg >> 3;
  int sw = (bid & 7) * cpx + (bid >> 3);
  int bx = sw % gridDim.x, by = sw / gridDim.x;
  const int bm = by * 128, bn = bx * 128;

  f32x4 acc[4][4];
#pragma unroll
  for (int i = 0; i < 4; ++i)
#pragma unroll
    for (int j = 0; j < 4; ++j)
      acc[i][j] = (f32x4){0.f, 0.f, 0.f, 0.f};

  const bool isA = (wid < 2);
  ushort* lbase = isA ? As : Bs;
  const int rowbase0 = isA ? bm : bn;
  const int chunk0 = (wid & 1) * 8;

  for (int p = 0; p < P; ++p) {
    int ai = (apack >> (2 * p)) & 3;
    int bi = (bpack >> (2 * p)) & 3;
    const ushort* Ap = ai == 0 ? A0 : (ai == 1 ? A1 : A2);
    const ushort* Bp = bi == 0 ? B0 : (bi == 1 ? B1 : B2);
    const ushort* gsrc = isA ? Ap : Bp;
    for (int k0 = 0; k0 < K; k0 += 64) {
      __syncthreads();
#pragma unroll
      for (int c = 0; c < 8; ++c) {
        int chunk = chunk0 + c;
        int row = chunk * 8 + lrow;
        const ushort* g = gsrc + (size_t)(rowbase0 + row) * K + k0 + (lslot << 3);
        __builtin_amdgcn_global_load_lds(
            (const __attribute__((address_space(1))) void*)(g),
            (__attribute__((address_space(3))) void*)(lbase + chunk * 512),
            16, 0, 0);
      }
      __syncthreads();
#pragma unroll
      for (int kk = 0; kk < 2; ++kk) {
        int sp = ((kk << 2) | lhi) ^ rswz;
        bf16x8 af[4], bg[4];
#pragma unroll
        for (int i = 0; i < 4; ++i)
          af[i] = *(const bf16x8*)(As + (wr * 64 + i * 16 + lane15) * 64 + sp * 8);
#pragma unroll
        for (int j = 0; j < 4; ++j)
          bg[j] = *(const bf16x8*)(Bs + (wc * 64 + j * 16 + lane15) * 64 + sp * 8);
#pragma unroll
        for (int i = 0; i < 4; ++i)
#pragma unroll
          for (int j = 0; j < 4; ++j)
            acc[i][j] = __builtin_amdgcn_mfma_f32_16x16x32_bf16(
                af[i], bg[j], acc[i][j], 0, 0, 0);
      }
    }
  }

#pragma unroll
  for (int j = 0; j < 4; ++j) {
    int col = bn + wc * 64 + j * 16 + lane15;
#pragma unroll
    for (int i = 0; i < 4; ++i) {
      f32x4 v = acc[i][j];
      int r0 = bm + wr * 64 + i * 16 + lhi * 4;
      if (accum) {
#pragma unroll
        for (int r = 0; r < 4; ++r) {
          size_t idx = (size_t)(r0 + r) * N + col;
          C[idx] = C[idx] + v[r];
        }
      } else {
#pragma unroll
        for (int r = 0; r < 4; ++r)
          C[(size_t)(r0 + r) * N + col] = v[r];
      }
    }
  }
}

// ---------------------------------------------------------------------------
// gemm_lif: whole layer. BM=256, BN=128, BK=64, 8 waves (4Mx2N), up to 3
// passes x up to 3 B-segments (dummy B stages keep vmcnt ledger uniform).
// accM = (pass0,seg0) chain; accC = all correction terms. Epilogue: in-LDS
// LIF scan over 2 row-groups (2 batches each), swizzled bf16 spike store.
// smode: 0 -> mode-1 spike layout (next gemm_lif), 1 -> mode-0 (gemm_seg).
// ---------------------------------------------------------------------------
__global__ __launch_bounds__(512, 2) void gemm_lif(
    PassArgs P, int npass, int nbpack, int K, int N, int ksh,
    const float* __restrict__ bias, ushort* __restrict__ spk, int smode)
{
  __shared__ __align__(16) ushort lds[81920];  // 160 KB

  const int tid = threadIdx.x;
  const int lane = tid & 63;
  const int wid = tid >> 6;        // 0..7
  const int wm = wid >> 1;         // 0..3 (64-row strip)
  const int wn = wid & 1;          // 0..1 (64-col strip)
  const int lane15 = lane & 15;
  const int lhi = lane >> 4;
  const int sg2 = lhi ^ ((lane15 >> 1) & 3);   // mode-1 read granule

  // bijective XCD swizzle (nwg multiple of 8)
  int nwg = gridDim.x * gridDim.y;
  int bid = blockIdx.y * gridDim.x + blockIdx.x;
  int cpx = nwg >> 3;
  int sw = (bid & 7) * cpx + (bid >> 3);
  int bx = sw % gridDim.x, by = sw / gridDim.x;
  const int bm = by * 256, bn = bx * 128;

  const int NTP = 1 << ksh;        // K/64 tiles per pass
  const int NT = npass << ksh;

  // stage tile t (both halves, 2A+3B loads per half = 10) into dbuf dd
  auto stage = [&](int t, int dd) {
    int p = t >> ksh;
    int k0 = (t & (NTP - 1)) << 6;
    const ushort* Ap = P.A[p];
#pragma unroll
    for (int h = 0; h < 2; ++h) {
      int kh = k0 + h * 32;
#pragma unroll
      for (int l = 0; l < 2; ++l) {
        int G = tid + l * 512;
        int row = G >> 2, gc = G & 3;
        __builtin_amdgcn_global_load_lds(
            (const __attribute__((address_space(1))) void*)(Ap + (size_t)(bm + row) * K + kh + gc * 8),
            (__attribute__((address_space(3))) void*)(lds + (dd * 2 + h) * 8192 + row * 32 + gc * 8),
            16, 0, 0);
      }
      int brow = tid >> 2, bgc = tid & 3;
#pragma unroll
      for (int s = 0; s < 3; ++s) {
        const ushort* Bp = P.B[p][s];
        __builtin_amdgcn_global_load_lds(
            (const __attribute__((address_space(1))) void*)(Bp + (size_t)(bn + brow) * K + kh + bgc * 8),
            (__attribute__((address_space(3))) void*)(lds + 32768 + ((dd * 2 + h) * 3 + s) * 4096 + brow * 32 + bgc * 8),
            16, 0, 0);
      }
    }
  };

  f32x4 accM[4][4], accC[4][4];
#pragma unroll
  for (int i = 0; i < 4; ++i)
#pragma unroll
    for (int j = 0; j < 4; ++j) {
      accM[i][j] = (f32x4){0.f, 0.f, 0.f, 0.f};
      accC[i][j] = (f32x4){0.f, 0.f, 0.f, 0.f};
    }

  // prologue: stage tile 0 into dbuf 0
  stage(0, 0);
  asm volatile("s_waitcnt vmcnt(0)" ::: "memory");
  __builtin_amdgcn_s_barrier();

  for (int t = 0; t < NT; ++t) {
    const int d = t & 1;
    const int tn = (t + 1 < NT) ? (t + 1) : (NT - 1);
    stage(tn, d ^ 1);                              // 10 loads (dummy at tail)
    asm volatile("s_waitcnt vmcnt(10)" ::: "memory");  // drains tile t
    __builtin_amdgcn_s_barrier();

    int p = t >> ksh;
    int nb = (nbpack >> (2 * p)) & 3;

    bf16x8 af[8];
#pragma unroll
    for (int h = 0; h < 2; ++h)
#pragma unroll
      for (int i = 0; i < 4; ++i)
        af[h * 4 + i] = *(const bf16x8*)(lds + (d * 2 + h) * 8192 +
                                         (wm * 64 + i * 16 + lane15) * 32 + sg2 * 8);

    __builtin_amdgcn_s_setprio(1);
#pragma unroll
    for (int h = 0; h < 2; ++h) {
#pragma unroll
      for (int s = 0; s < 3; ++s) {
        if (s < nb) {
          bf16x8 bf[4];
#pragma unroll
          for (int j = 0; j < 4; ++j)
            bf[j] = *(const bf16x8*)(lds + 32768 + ((d * 2 + h) * 3 + s) * 4096 +
                                     (wn * 64 + j * 16 + lane15) * 32 + sg2 * 8);
          if (p == 0 && s == 0) {
#pragma unroll
            for (int i = 0; i < 4; ++i)
#pragma unroll
              for (int j = 0; j < 4; ++j)
                accM[i][j] = __builtin_amdgcn_mfma_f32_16x16x32_bf16(
                    af[h * 4 + i], bf[j], accM[i][j], 0, 0, 0);
          } else {
#pragma unroll
            for (int i = 0; i < 4; ++i)
#pragma unroll
              for (int j = 0; j < 4; ++j)
                accC[i][j] = __builtin_amdgcn_mfma_f32_16x16x32_bf16(
                    af[h * 4 + i], bf[j], accC[i][j], 0, 0, 0);
          }
        }
      }
    }
    __builtin_amdgcn_s_setprio(0);
    __builtin_amdgcn_s_barrier();
  }

  // ---- epilogue: fused LIF (2 groups of 128 rows = 2 batches each) ----
  asm volatile("s_waitcnt vmcnt(0)" ::: "memory");  // drain tail dummies
  __builtin_amdgcn_s_barrier();

  float* curb = (float*)lds;       // [128][130] fp32 (66.6 KB)
  const int wgrp = wm >> 1;        // 0..1

  for (int g = 0; g < 2; ++g) {
    if (wgrp == g) {
#pragma unroll
      for (int i = 0; i < 4; ++i) {
        int rl = (wm & 1) * 64 + i * 16 + lhi * 4;
#pragma unroll
        for (int j = 0; j < 4; ++j) {
          int c = wn * 64 + j * 16 + lane15;
#pragma unroll
          for (int r = 0; r < 4; ++r)
            curb[(rl + r) * 130 + c] = accM[i][j][r] + accC[i][j][r];
        }
      }
    }
    __builtin_amdgcn_s_barrier();
    if (tid < 256) {
      int bl = tid >> 7, n = tid & 127;
      int cg = bn + n;
      float bv = bias[cg];
      int nb6 = cg >> 6;
      int sl = (cg >> 3) & 7;
      int nlow = cg & 7;
      int mbase = bm + g * 128 + bl * 64;
      float mem = 0.f;
      for (int t2 = 0; t2 < 64; ++t2) {
        float c = __fadd_rn(curb[(bl * 64 + t2) * 130 + n], bv);
        float reset = ((mem - 1.0f) > 0.0f) ? 1.0f : 0.0f;
        mem = __fmul_rn(BETA, mem);
        mem = __fadd_rn(mem, c);
        mem = __fadd_rn(mem, -reset);
        ushort sv = ((mem - 1.0f) > 0.0f) ? (ushort)0x3F80 : (ushort)0;
        int m = mbase + t2;
        int ps = smode ? (sl ^ (m & 7))
                       : ((sl & 4) | ((sl & 3) ^ ((m >> 1) & 3)));
        spk[(size_t)m * N + (nb6 << 6) + (ps << 3) + nlow] = sv;
      }
    }
    __builtin_amdgcn_s_barrier();
  }
}

// Final layer helper: LIF emitting spk3+mem3 (fp32) from cur.
__global__ __launch_bounds__(256) void lif_final(
    const float* __restrict__ cur_in, const float* __restrict__ bias,
    float* __restrict__ spk_out, float* __restrict__ mem_out, int N, int total)
{
  int g = blockIdx.x * 256 + threadIdx.x;
  if (g >= total) return;
  int b = g / N, n = g - b * N;
  size_t base = (size_t)b * T_ * N + n;
  float bv = bias[n];
  float mem = 0.f;
  for (int t = 0; t < T_; ++t) {
    size_t idx = base + (size_t)t * N;
    float c = __fadd_rn(cur_in[idx], bv);
    float reset = ((mem - 1.0f) > 0.0f) ? 1.0f : 0.0f;
    mem = __fmul_rn(BETA, mem);
    mem = __fadd_rn(mem, c);
    mem = __fadd_rn(mem, -reset);
    spk_out[idx] = ((mem - 1.0f) > 0.0f) ? 1.0f : 0.0f;
    mem_out[idx] = mem;
  }
}

extern "C" void kernel_launch(void* const* d_in, const int* in_sizes, int n_in,
                              void* d_out, int out_size, void* d_ws, size_t ws_size,
                              hipStream_t stream)
{
  const float* x  = (const float*)d_in[0];
  const float* W0 = (const float*)d_in[1];
  const float* b0 = (const float*)d_in[2];
  const float* W1 = (const float*)d_in[3];
  const float* b1 = (const float*)d_in[4];
  const float* W2 = (const float*)d_in[5];
  const float* b2 = (const float*)d_in[6];
  const float* W3 = (const float*)d_in[7];
  const float* b3 = (const float*)d_in[8];
  float* out = (float*)d_out;

  char* ws = (char*)d_ws;
  size_t off = 0;
  auto take = [&](size_t bytes) -> char* {
    char* p = ws + off;
    off += (bytes + 255) & ~(size_t)255;
    return p;
  };

  ushort* w0s[3], *w1s[3], *w2s[3], *w3s[3], *xs[3];
  for (int i = 0; i < 3; ++i) w0s[i] = (ushort*)take((size_t)2048 * 2048 * 2);
  for (int i = 0; i < 3; ++i) w1s[i] = (ushort*)take((size_t)2048 * 2048 * 2);
  for (int i = 0; i < 3; ++i) w2s[i] = (ushort*)take((size_t)1024 * 2048 * 2);
  for (int i = 0; i < 3; ++i) w3s[i] = (ushort*)take((size_t)128 * 1024 * 2);
  for (int i = 0; i < 3; ++i) xs[i]  = (ushort*)take((size_t)M_ * 2048 * 2);
  ushort* s0 = (ushort*)take((size_t)M_ * 2048 * 2);  // cannot alias xs (race)
  float* cur = (float*)take((size_t)M_ * NOUT * 4);   // L3 only (4MB)
  // s1/s2 alias xs[1]/xs[2] (dead after L0 completes, stream-ordered)
  ushort* s1 = xs[1];
  ushort* s2 = xs[2];

  dim3 blk(256);
  dim3 fblk(512);

  // --- splits: mode 1 for gemm_lif operands; mode 0 for W3 (gemm_seg) ---
  {
    int ns = 2048 * 2048 / 8;
    split3_swz<<<(ns + 255) / 256, blk, 0, stream>>>(W0, w0s[0], w0s[1], w0s[2], 2048, ns, 1);
    split3_swz<<<(ns + 255) / 256, blk, 0, stream>>>(W1, w1s[0], w1s[1], w1s[2], 2048, ns, 1);
    ns = 1024 * 2048 / 8;
    split3_swz<<<(ns + 255) / 256, blk, 0, stream>>>(W2, w2s[0], w2s[1], w2s[2], 2048, ns, 1);
    ns = 128 * 1024 / 8;
    split3_swz<<<(ns + 255) / 256, blk, 0, stream>>>(W3, w3s[0], w3s[1], w3s[2], 1024, ns, 0);
    ns = M_ * 2048 / 8;
    split3_swz<<<(ns + 255) / 256, blk, 0, stream>>>(x, xs[0], xs[1], xs[2], 2048, ns, 1);
  }

  // --- L0: one launch, 3 passes (x1:{w1,w2,w3}, x2:{w1,w2}, x3:{w1}) ---
  {
    PassArgs P;
    P.A[0] = xs[0]; P.A[1] = xs[1]; P.A[2] = xs[2];
    P.B[0][0] = w0s[0]; P.B[0][1] = w0s[1]; P.B[0][2] = w0s[2];
    P.B[1][0] = w0s[0]; P.B[1][1] = w0s[1]; P.B[1][2] = w0s[1];  // dummy seg2
    P.B[2][0] = w0s[0]; P.B[2][1] = w0s[0]; P.B[2][2] = w0s[0];  // dummy seg1,2
    int nbpack = 3 | (2 << 2) | (1 << 4);
    gemm_lif<<<dim3(16, 32), fblk, 0, stream>>>(P, 3, nbpack, 2048, 2048, 5, b0, s0, 0);
  }
  // --- L1: one launch ---
  {
    PassArgs P;
    P.A[0] = s0; P.A[1] = s0; P.A[2] = s0;
    P.B[0][0] = w1s[0]; P.B[0][1] = w1s[1]; P.B[0][2] = w1s[2];
    P.B[1][0] = w1s[0]; P.B[1][1] = w1s[0]; P.B[1][2] = w1s[0];
    P.B[2][0] = w1s[0]; P.B[2][1] = w1s[0]; P.B[2][2] = w1s[0];
    gemm_lif<<<dim3(16, 32), fblk, 0, stream>>>(P, 1, 3, 2048, 2048, 5, b1, s1, 0);
  }
  // --- L2: one launch (spikes in mode-0 for gemm_seg) ---
  {
    PassArgs P;
    P.A[0] = s1; P.A[1] = s1; P.A[2] = s1;
    P.B[0][0] = w2s[0]; P.B[0][1] = w2s[1]; P.B[0][2] = w2s[2];
    P.B[1][0] = w2s[0]; P.B[1][1] = w2s[0]; P.B[1][2] = w2s[0];
    P.B[2][0] = w2s[0]; P.B[2][1] = w2s[0]; P.B[2][2] = w2s[0];
    gemm_lif<<<dim3(8, 32), fblk, 0, stream>>>(P, 1, 3, 2048, 1024, 5, b2, s2, 1);
  }
  // --- L3 (gemm_seg, mode-0) + final LIF ---
  {
    dim3 grid(128 / 128, M_ / 128);
    gemm_seg<<<grid, blk, 0, stream>>>(s2, s2, s2, w3s[0], w3s[1], w3s[2],
                                       1, 0, 0, 1024, 128, 0, cur);
    gemm_seg<<<grid, blk, 0, stream>>>(s2, s2, s2, w3s[0], w3s[1], w3s[2],
                                       2, 0, 1 | (2 << 2), 1024, 128, 1, cur);
    float* spk3 = out;
    float* mem3 = out + (size_t)M_ * NOUT;
    lif_final<<<(B_ * NOUT) / 256, blk, 0, stream>>>(cur, b3, spk3, mem3, NOUT, B_ * NOUT);
  }
}

// Round 13
// 591.624 us; speedup vs baseline: 2.7735x; 1.4981x over previous
//
#include <hip/hip_runtime.h>
#include <cstddef>
#include <cstdint>

// SNN: 4x (Linear + LIF). NEW: fp16 2-term exact splitting (11-bit halves;
// f16xf16 products exact in fp32) cuts MFMA work 728->416 GF vs bf16 3-term.
//   w = wh + 2^-12 * wl'   (wl' = f16((w-wh)*4096))
//   L0: xh*wh (main) ; corr chain { xh*wl', xl'*wh } at scale 2^12
//   L1-3: s*wh (main) ; s*wl' (corr)       [spikes exact in fp16]
// Scale-segregated dual accumulators; cur = fma(curC, 2^-12, curM) + bias.
// gemm2<NB,MODE> clones R10's proven 1062-TF schedule (BM256xBN128, BK=64,
// 8 waves, k-half dbuf staging, counted vmcnt(2+NB), mode-1 swizzle).
// L3 keeps R10's bf16 gemm_seg path verbatim (mode-0 operands).

#define BETA 0.95f

static constexpr int B_ = 128;
static constexpr int T_ = 64;
static constexpr int M_ = B_ * T_;       // 8192 rows
static constexpr int NOUT = 128;

typedef __bf16 bf16x8 __attribute__((ext_vector_type(8)));
typedef _Float16 f16x8 __attribute__((ext_vector_type(8)));
typedef float f32x4 __attribute__((ext_vector_type(4)));
typedef ushort u16x8 __attribute__((ext_vector_type(8)));

__device__ __forceinline__ ushort f32_bf16_rne(float f) {
  uint32_t u = __float_as_uint(f);
  uint32_t r = u + 0x7FFFu + ((u >> 16) & 1u);
  return (ushort)(r >> 16);
}
__device__ __forceinline__ float bf16_f32(ushort h) {
  return __uint_as_float(((uint32_t)h) << 16);
}
__device__ __forceinline__ ushort h2u(_Float16 h) {
  union { _Float16 h; ushort u; } v; v.h = h; return v.u;
}
__device__ __forceinline__ _Float16 u2h(ushort u) {
  union { ushort u; _Float16 h; } v; v.u = u; return v.h;
}

// ---------------------------------------------------------------------------
// fp32 -> 2 fp16 exact split (h + 2^-12 * l'), mode-1 swizzled positions:
// stored slot = (slot&4)|((slot&3)^((row>>1)&3)). Subnormal-safe: |h|<2^-14
// is zeroed so the value flows entirely through l' (MFMA flush immunity).
// ---------------------------------------------------------------------------
__global__ __launch_bounds__(256) void split2_f16(
    const float* __restrict__ S, ushort* __restrict__ oh,
    ushort* __restrict__ ol, int K, int nslots)
{
  int g = blockIdx.x * 256 + threadIdx.x;
  if (g >= nslots) return;
  int spr = K >> 3;
  int row = g / spr;
  int sl = g - row * spr;
  int kb = sl >> 3;
  int slot = sl & 7;
  int pslot = (slot & 4) | ((slot & 3) ^ ((row >> 1) & 3));
  const float* src = S + (size_t)row * K + (kb << 6) + (slot << 3);
  size_t dst = (size_t)row * K + (kb << 6) + (pslot << 3);
  u16x8 vh, vl;
#pragma unroll
  for (int i = 0; i < 8; ++i) {
    float f = src[i];
    _Float16 h = (_Float16)f;
    float hf = (float)h;
    if (fabsf(hf) < 6.103515625e-05f) { h = (_Float16)0.0f; hf = 0.0f; }
    float l = (f - hf) * 4096.0f;
    _Float16 hl = (_Float16)l;
    vh[i] = h2u(h);
    vl[i] = h2u(hl);
  }
  *reinterpret_cast<u16x8*>(oh + dst) = vh;
  *reinterpret_cast<u16x8*>(ol + dst) = vl;
}

// ---------------------------------------------------------------------------
// fp32 -> 3 bf16 exact split, mode-0 swizzle (L3 gemm_seg operands only).
// ---------------------------------------------------------------------------
__global__ __launch_bounds__(256) void split3_swz(
    const float* __restrict__ S, ushort* __restrict__ o1,
    ushort* __restrict__ o2, ushort* __restrict__ o3,
    int K, int nslots)
{
  int g = blockIdx.x * 256 + threadIdx.x;
  if (g >= nslots) return;
  int spr = K >> 3;
  int row = g / spr;
  int sl = g - row * spr;
  int kb = sl >> 3;
  int slot = sl & 7;
  int pslot = slot ^ (row & 7);
  const float* src = S + (size_t)row * K + (kb << 6) + (slot << 3);
  size_t dst = (size_t)row * K + (kb << 6) + (pslot << 3);
  u16x8 v1, v2, v3;
#pragma unroll
  for (int i = 0; i < 8; ++i) {
    float f = src[i];
    ushort h1 = f32_bf16_rne(f);
    float r = f - bf16_f32(h1);
    ushort h2 = f32_bf16_rne(r);
    float r2 = r - bf16_f32(h2);
    ushort h3 = f32_bf16_rne(r2);
    v1[i] = h1; v2[i] = h2; v3[i] = h3;
  }
  *reinterpret_cast<u16x8*>(o1 + dst) = v1;
  *reinterpret_cast<u16x8*>(o2 + dst) = v2;
  *reinterpret_cast<u16x8*>(o3 + dst) = v3;
}

// ---------------------------------------------------------------------------
// gemm_seg (L3 only, bf16, mode-0): 128x128 tile, BK=64, 4 waves. Verbatim R10.
// ---------------------------------------------------------------------------
__global__ __launch_bounds__(256) void gemm_seg(
    const ushort* __restrict__ A0, const ushort* __restrict__ A1,
    const ushort* __restrict__ A2,
    const ushort* __restrict__ B0, const ushort* __restrict__ B1,
    const ushort* __restrict__ B2,
    int P, int apack, int bpack, int K, int N, int accum,
    float* __restrict__ C)
{
  __shared__ ushort As[128 * 64];
  __shared__ ushort Bs[128 * 64];

  const int tid = threadIdx.x;
  const int lane = tid & 63;
  const int wid = tid >> 6;
  const int wr = wid >> 1, wc = wid & 1;
  const int lane15 = lane & 15;
  const int lhi = lane >> 4;
  const int rswz = lane15 & 7;
  const int lrow = lane >> 3, lslot = lane & 7;

  int nwg = gridDim.x * gridDim.y;
  int bid = blockIdx.y * gridDim.x + blockIdx.x;
  int cpx = nwg >> 3;
  int sw = (bid & 7) * cpx + (bid >> 3);
  int bx = sw % gridDim.x, by = sw / gridDim.x;
  const int bm = by * 128, bn = bx * 128;

  f32x4 acc[4][4];
#pragma unroll
  for (int i = 0; i < 4; ++i)
#pragma unroll
    for (int j = 0; j < 4; ++j)
      acc[i][j] = (f32x4){0.f, 0.f, 0.f, 0.f};

  const bool isA = (wid < 2);
  ushort* lbase = isA ? As : Bs;
  const int rowbase0 = isA ? bm : bn;
  const int chunk0 = (wid & 1) * 8;

  for (int p = 0; p < P; ++p) {
    int ai = (apack >> (2 * p)) & 3;
    int bi = (bpack >> (2 * p)) & 3;
    const ushort* Ap = ai == 0 ? A0 : (ai == 1 ? A1 : A2);
    const ushort* Bp = bi == 0 ? B0 : (bi == 1 ? B1 : B2);
    const ushort* gsrc = isA ? Ap : Bp;
    for (int k0 = 0; k0 < K; k0 += 64) {
      __syncthreads();
#pragma unroll
      for (int c = 0; c < 8; ++c) {
        int chunk = chunk0 + c;
        int row = chunk * 8 + lrow;
        const ushort* g = gsrc + (size_t)(rowbase0 + row) * K + k0 + (lslot << 3);
        __builtin_amdgcn_global_load_lds(
            (const __attribute__((address_space(1))) void*)(g),
            (__attribute__((address_space(3))) void*)(lbase + chunk * 512),
            16, 0, 0);
      }
      __syncthreads();
#pragma unroll
      for (int kk = 0; kk < 2; ++kk) {
        int sp = ((kk << 2) | lhi) ^ rswz;
        bf16x8 af[4], bg[4];
#pragma unroll
        for (int i = 0; i < 4; ++i)
          af[i] = *(const bf16x8*)(As + (wr * 64 + i * 16 + lane15) * 64 + sp * 8);
#pragma unroll
        for (int j = 0; j < 4; ++j)
          bg[j] = *(const bf16x8*)(Bs + (wc * 64 + j * 16 + lane15) * 64 + sp * 8);
#pragma unroll
        for (int i = 0; i < 4; ++i)
#pragma unroll
          for (int j = 0; j < 4; ++j)
            acc[i][j] = __builtin_amdgcn_mfma_f32_16x16x32_bf16(
                af[i], bg[j], acc[i][j], 0, 0, 0);
      }
    }
  }

#pragma unroll
  for (int j = 0; j < 4; ++j) {
    int col = bn + wc * 64 + j * 16 + lane15;
#pragma unroll
    for (int i = 0; i < 4; ++i) {
      f32x4 v = acc[i][j];
      int r0 = bm + wr * 64 + i * 16 + lhi * 4;
      if (accum) {
#pragma unroll
        for (int r = 0; r < 4; ++r) {
          size_t idx = (size_t)(r0 + r) * N + col;
          C[idx] = C[idx] + v[r];
        }
      } else {
#pragma unroll
        for (int r = 0; r < 4; ++r)
          C[(size_t)(r0 + r) * N + col] = v[r];
      }
    }
  }
}

// ---------------------------------------------------------------------------
// gemm2<NB, MODE>: fp16 clone of R10's gemm_fused. BM=256, BN=128, BK=64,
// 8 waves (4Mx2N). NT=K/64 runtime. Per k-half phase: af[4] read once,
// NB B-segs {bf read + 16 MFMA}; stage (t+1,h) into dbuf d^1 (2A+NB B
// loads); counted vmcnt(2+NB); 2 barriers/phase. Mode-1 swizzle.
// MODE 0: seg0->accM, seg1->accC; curM = accM, curC = f16(accC).
// MODE 1: all segs->accC; curC += accC (fp16 RMW, tile-exclusive).
// ---------------------------------------------------------------------------
template<int NB, int MODE>
__global__ __launch_bounds__(512) void gemm2(
    const ushort* __restrict__ A,
    const ushort* __restrict__ Bs0, const ushort* __restrict__ Bs1,
    int NT, int K, int N,
    float* __restrict__ curM, ushort* __restrict__ curC)
{
  __shared__ __align__(16) ushort lds[32768 + 2 * 2 * NB * 4096];

  const int tid = threadIdx.x;
  const int lane = tid & 63;
  const int wid = tid >> 6;        // 0..7
  const int wm = wid >> 1;         // 0..3 (64-row M strip)
  const int wn = wid & 1;          // 0..1 (64-col N strip)
  const int lane15 = lane & 15;
  const int lhi = lane >> 4;
  const int sg2 = lhi ^ ((lane15 >> 1) & 3);   // mode-1 read granule

  // bijective XCD swizzle (nwg multiple of 8)
  int nwg = gridDim.x * gridDim.y;
  int bid = blockIdx.y * gridDim.x + blockIdx.x;
  int cpx = nwg >> 3;
  int sw = (bid & 7) * cpx + (bid >> 3);
  int bx = sw % gridDim.x, by = sw / gridDim.x;
  const int bm = by * 256, bn = bx * 128;

  const int sr2 = tid >> 2;   // 0..127
  const int sg = tid & 3;     // 16B granule

  auto stage = [&](int t1, int h, int d) {
    const int k0 = t1 * 64 + h * 32;
#pragma unroll
    for (int l = 0; l < 2; ++l) {
      int row = sr2 + l * 128;
      __builtin_amdgcn_global_load_lds(
          (const __attribute__((address_space(1))) void*)(A + (size_t)(bm + row) * K + k0 + sg * 8),
          (__attribute__((address_space(3))) void*)(lds + d * 16384 + h * 8192 + row * 32 + sg * 8),
          16, 0, 0);
    }
#pragma unroll
    for (int s = 0; s < NB; ++s) {
      const ushort* Bp = (s == 0) ? Bs0 : Bs1;
      __builtin_amdgcn_global_load_lds(
          (const __attribute__((address_space(1))) void*)(Bp + (size_t)(bn + sr2) * K + k0 + sg * 8),
          (__attribute__((address_space(3))) void*)(lds + 32768 + ((d * 2 + h) * NB + s) * 4096 + sr2 * 32 + sg * 8),
          16, 0, 0);
    }
  };

  f32x4 accM[4][4], accC[4][4];
#pragma unroll
  for (int i = 0; i < 4; ++i)
#pragma unroll
    for (int j = 0; j < 4; ++j) {
      accM[i][j] = (f32x4){0.f, 0.f, 0.f, 0.f};
      accC[i][j] = (f32x4){0.f, 0.f, 0.f, 0.f};
    }

  // prologue: stage tile 0 halves into dbuf 0; confirm half 0
  stage(0, 0, 0);
  stage(0, 1, 0);
  if constexpr (NB == 2) asm volatile("s_waitcnt vmcnt(4)" ::: "memory");
  if constexpr (NB == 1) asm volatile("s_waitcnt vmcnt(3)" ::: "memory");
  asm volatile("s_barrier" ::: "memory");

  for (int t = 0; t < NT; ++t) {
    const int d = t & 1;
#pragma unroll
    for (int h = 0; h < 2; ++h) {
      f16x8 af[4];
      const ushort* Ab = lds + (d * 2 + h) * 8192;
#pragma unroll
      for (int i = 0; i < 4; ++i)
        af[i] = *(const f16x8*)(Ab + (wm * 64 + i * 16 + lane15) * 32 + sg2 * 8);

      if (t < NT - 1) {
        stage(t + 1, h, d ^ 1);
        if constexpr (NB == 2) asm volatile("s_waitcnt vmcnt(4)" ::: "memory");
        if constexpr (NB == 1) asm volatile("s_waitcnt vmcnt(3)" ::: "memory");
      } else if (h == 0) {
        asm volatile("s_waitcnt vmcnt(0)" ::: "memory");
      }
      asm volatile("s_barrier" ::: "memory");

      __builtin_amdgcn_s_setprio(1);
#pragma unroll
      for (int s = 0; s < NB; ++s) {
        const ushort* Bb = lds + 32768 + ((d * 2 + h) * NB + s) * 4096;
        f16x8 bf[4];
#pragma unroll
        for (int j = 0; j < 4; ++j)
          bf[j] = *(const f16x8*)(Bb + (wn * 64 + j * 16 + lane15) * 32 + sg2 * 8);
        if (MODE == 0 && s == 0) {
#pragma unroll
          for (int i = 0; i < 4; ++i)
#pragma unroll
            for (int j = 0; j < 4; ++j)
              accM[i][j] = __builtin_amdgcn_mfma_f32_16x16x32_f16(af[i], bf[j], accM[i][j], 0, 0, 0);
        } else {
#pragma unroll
          for (int i = 0; i < 4; ++i)
#pragma unroll
            for (int j = 0; j < 4; ++j)
              accC[i][j] = __builtin_amdgcn_mfma_f32_16x16x32_f16(af[i], bf[j], accC[i][j], 0, 0, 0);
        }
      }
      __builtin_amdgcn_s_setprio(0);
      asm volatile("s_barrier" ::: "memory");
    }
  }

  // epilogue: C/D layout col = lane&15, row = (lane>>4)*4 + reg
#pragma unroll
  for (int i = 0; i < 4; ++i) {
    int r0 = bm + wm * 64 + i * 16 + lhi * 4;
#pragma unroll
    for (int j = 0; j < 4; ++j) {
      int col = bn + wn * 64 + j * 16 + lane15;
      f32x4 vc = accC[i][j];
      if (MODE == 0) {
        f32x4 vm = accM[i][j];
#pragma unroll
        for (int r = 0; r < 4; ++r) {
          size_t idx = (size_t)(r0 + r) * N + col;
          curM[idx] = vm[r];
          curC[idx] = h2u((_Float16)vc[r]);
        }
      } else {
#pragma unroll
        for (int r = 0; r < 4; ++r) {
          size_t idx = (size_t)(r0 + r) * N + col;
          float old = (float)u2h(curC[idx]);
          curC[idx] = h2u((_Float16)(old + vc[r]));
        }
      }
    }
  }
}

// ---------------------------------------------------------------------------
// LIF: cur = fma(curC, 2^-12, curM) + bias (two roundings). Spikes written
// swizzled: fmt=1 -> fp16 {0,0x3C00} mode-1 (gemm2 A); fmt=0 -> bf16
// {0,0x3F80} mode-0 (gemm_seg A).
// ---------------------------------------------------------------------------
__global__ __launch_bounds__(256) void lif_comb(
    const float* __restrict__ curM, const ushort* __restrict__ curC,
    const float* __restrict__ bias, ushort* __restrict__ spk,
    int N, int total, int fmt)
{
  int g = blockIdx.x * 256 + threadIdx.x;
  if (g >= total) return;
  int b = g / N, n = g - b * N;
  int nb = n >> 6;
  int slot = (n >> 3) & 7;
  int nlow = n & 7;
  float bv = bias[n];
  const ushort one = fmt ? (ushort)0x3C00 : (ushort)0x3F80;
  float mem = 0.f;
  for (int t = 0; t < T_; ++t) {
    int m = b * T_ + t;
    size_t idx = (size_t)m * N + n;
    float mm = __fmaf_rn((float)u2h(curC[idx]), 2.44140625e-4f, curM[idx]);
    float c = __fadd_rn(mm, bv);
    float reset = ((mem - 1.0f) > 0.0f) ? 1.0f : 0.0f;
    mem = __fmul_rn(BETA, mem);
    mem = __fadd_rn(mem, c);
    mem = __fadd_rn(mem, -reset);
    ushort sv = ((mem - 1.0f) > 0.0f) ? one : (ushort)0;
    int ps = fmt ? ((slot & 4) | ((slot & 3) ^ ((m >> 1) & 3)))
                 : (slot ^ (m & 7));
    spk[(size_t)m * N + (nb << 6) + (ps << 3) + nlow] = sv;
  }
}

// Final layer: LIF from fp32 cur (L3 path), emit spk3+mem3.
__global__ __launch_bounds__(256) void lif_final(
    const float* __restrict__ cur_in, const float* __restrict__ bias,
    float* __restrict__ spk_out, float* __restrict__ mem_out, int N, int total)
{
  int g = blockIdx.x * 256 + threadIdx.x;
  if (g >= total) return;
  int b = g / N, n = g - b * N;
  size_t base = (size_t)b * T_ * N + n;
  float bv = bias[n];
  float mem = 0.f;
  for (int t = 0; t < T_; ++t) {
    size_t idx = base + (size_t)t * N;
    float c = __fadd_rn(cur_in[idx], bv);
    float reset = ((mem - 1.0f) > 0.0f) ? 1.0f : 0.0f;
    mem = __fmul_rn(BETA, mem);
    mem = __fadd_rn(mem, c);
    mem = __fadd_rn(mem, -reset);
    spk_out[idx] = ((mem - 1.0f) > 0.0f) ? 1.0f : 0.0f;
    mem_out[idx] = mem;
  }
}

extern "C" void kernel_launch(void* const* d_in, const int* in_sizes, int n_in,
                              void* d_out, int out_size, void* d_ws, size_t ws_size,
                              hipStream_t stream)
{
  const float* x  = (const float*)d_in[0];
  const float* W0 = (const float*)d_in[1];
  const float* b0 = (const float*)d_in[2];
  const float* W1 = (const float*)d_in[3];
  const float* b1 = (const float*)d_in[4];
  const float* W2 = (const float*)d_in[5];
  const float* b2 = (const float*)d_in[6];
  const float* W3 = (const float*)d_in[7];
  const float* b3 = (const float*)d_in[8];
  float* out = (float*)d_out;

  char* ws = (char*)d_ws;
  size_t off = 0;
  auto take = [&](size_t bytes) -> char* {
    char* p = ws + off;
    off += (bytes + 255) & ~(size_t)255;
    return p;
  };

  ushort* w0h = (ushort*)take((size_t)2048 * 2048 * 2);
  ushort* w0l = (ushort*)take((size_t)2048 * 2048 * 2);
  ushort* w1h = (ushort*)take((size_t)2048 * 2048 * 2);
  ushort* w1l = (ushort*)take((size_t)2048 * 2048 * 2);
  ushort* w2h = (ushort*)take((size_t)1024 * 2048 * 2);
  ushort* w2l = (ushort*)take((size_t)1024 * 2048 * 2);
  ushort* w3s[3];
  for (int i = 0; i < 3; ++i) w3s[i] = (ushort*)take((size_t)128 * 1024 * 2);
  ushort* xh = (ushort*)take((size_t)M_ * 2048 * 2);
  ushort* xl = (ushort*)take((size_t)M_ * 2048 * 2);
  ushort* s0 = (ushort*)take((size_t)M_ * 2048 * 2);
  float* curM = (float*)take((size_t)M_ * 2048 * 4);
  ushort* curC = (ushort*)take((size_t)M_ * 2048 * 2);
  // s1 aliases xh, s2 aliases xl (both dead after L0 GEMMs, stream-ordered)
  ushort* s1 = xh;
  ushort* s2 = xl;

  dim3 blk(256);
  dim3 fblk(512);

  // --- splits ---
  {
    int ns = 2048 * 2048 / 8;
    split2_f16<<<(ns + 255) / 256, blk, 0, stream>>>(W0, w0h, w0l, 2048, ns);
    split2_f16<<<(ns + 255) / 256, blk, 0, stream>>>(W1, w1h, w1l, 2048, ns);
    ns = 1024 * 2048 / 8;
    split2_f16<<<(ns + 255) / 256, blk, 0, stream>>>(W2, w2h, w2l, 2048, ns);
    ns = 128 * 1024 / 8;
    split3_swz<<<(ns + 255) / 256, blk, 0, stream>>>(W3, w3s[0], w3s[1], w3s[2], 1024, ns);
    ns = M_ * 2048 / 8;
    split2_f16<<<(ns + 255) / 256, blk, 0, stream>>>(x, xh, xl, 2048, ns);
  }

  // --- L0: xh*{wh->M, wl->C}; then xl*{wh}->C ---
  {
    dim3 grid(2048 / 128, M_ / 256);   // (16, 32) = 512 blocks
    gemm2<2, 0><<<grid, fblk, 0, stream>>>(xh, w0h, w0l, 32, 2048, 2048, curM, curC);
    gemm2<1, 1><<<grid, fblk, 0, stream>>>(xl, w0h, w0h, 32, 2048, 2048, curM, curC);
    lif_comb<<<(B_ * 2048) / 256, blk, 0, stream>>>(curM, curC, b0, s0, 2048, B_ * 2048, 1);
  }
  // --- L1 ---
  {
    dim3 grid(2048 / 128, M_ / 256);
    gemm2<2, 0><<<grid, fblk, 0, stream>>>(s0, w1h, w1l, 32, 2048, 2048, curM, curC);
    lif_comb<<<(B_ * 2048) / 256, blk, 0, stream>>>(curM, curC, b1, s1, 2048, B_ * 2048, 1);
  }
  // --- L2 (spikes out in bf16 mode-0 for gemm_seg) ---
  {
    dim3 grid(1024 / 128, M_ / 256);   // (8, 32) = 256 blocks
    gemm2<2, 0><<<grid, fblk, 0, stream>>>(s1, w2h, w2l, 32, 2048, 1024, curM, curC);
    lif_comb<<<(B_ * 1024) / 256, blk, 0, stream>>>(curM, curC, b2, s2, 1024, B_ * 1024, 0);
  }
  // --- L3 (bf16 gemm_seg, verbatim R10) + final LIF ---
  {
    dim3 grid(128 / 128, M_ / 128);    // (1, 64)
    gemm_seg<<<grid, blk, 0, stream>>>(s2, s2, s2, w3s[0], w3s[1], w3s[2],
                                       1, 0, 0, 1024, 128, 0, curM);
    gemm_seg<<<grid, blk, 0, stream>>>(s2, s2, s2, w3s[0], w3s[1], w3s[2],
                                       2, 0, 1 | (2 << 2), 1024, 128, 1, curM);
    float* spk3 = out;
    float* mem3 = out + (size_t)M_ * NOUT;
    lif_final<<<(B_ * NOUT) / 256, blk, 0, stream>>>(curM, b3, spk3, mem3, NOUT, B_ * NOUT);
  }
}

// Round 14
// 478.813 us; speedup vs baseline: 3.4269x; 1.2356x over previous
//
#include <hip/hip_runtime.h>
#include <cstddef>
#include <cstdint>

// SNN: 4x (Linear + LIF). fp16 2-term exact splitting (R13, 416 GF) with
// FUSED in-LDS LIF epilogues (R14): no curM round-trip.
//   L0: corr pass (xl*wh -> curC f16) FIRST; main pass (xh*{wh->accM,
//       wl->accC}) combines corr = accC + curC in-epilogue, LIF, spikes.
//   L1/L2: single gemm_mainL launch each (accM/accC -> LIF -> spikes).
//   L3: single gemm_seg_lif (dual-acc bf16 3-split chain, identical
//       arithmetic order to R13's two launches, LIF -> spk3/mem3).
// LIF tile [256][132] f32 in LDS: store+scan both <=2-way bank-aliased.

#define BETA 0.95f

static constexpr int B_ = 128;
static constexpr int T_ = 64;
static constexpr int M_ = B_ * T_;       // 8192 rows
static constexpr int NOUT = 128;

typedef __bf16 bf16x8 __attribute__((ext_vector_type(8)));
typedef _Float16 f16x8 __attribute__((ext_vector_type(8)));
typedef float f32x4 __attribute__((ext_vector_type(4)));
typedef ushort u16x8 __attribute__((ext_vector_type(8)));

__device__ __forceinline__ ushort f32_bf16_rne(float f) {
  uint32_t u = __float_as_uint(f);
  uint32_t r = u + 0x7FFFu + ((u >> 16) & 1u);
  return (ushort)(r >> 16);
}
__device__ __forceinline__ float bf16_f32(ushort h) {
  return __uint_as_float(((uint32_t)h) << 16);
}
__device__ __forceinline__ ushort h2u(_Float16 h) {
  union { _Float16 h; ushort u; } v; v.h = h; return v.u;
}
__device__ __forceinline__ _Float16 u2h(ushort u) {
  union { ushort u; _Float16 h; } v; v.u = u; return v.h;
}

// ---------------------------------------------------------------------------
// fp32 -> 2 fp16 exact split (h + 2^-12 * l'), mode-1 swizzled positions.
// Subnormal-safe: |h|<2^-14 zeroed; value flows through l'.
// ---------------------------------------------------------------------------
__global__ __launch_bounds__(256) void split2_f16(
    const float* __restrict__ S, ushort* __restrict__ oh,
    ushort* __restrict__ ol, int K, int nslots)
{
  int g = blockIdx.x * 256 + threadIdx.x;
  if (g >= nslots) return;
  int spr = K >> 3;
  int row = g / spr;
  int sl = g - row * spr;
  int kb = sl >> 3;
  int slot = sl & 7;
  int pslot = (slot & 4) | ((slot & 3) ^ ((row >> 1) & 3));
  const float* src = S + (size_t)row * K + (kb << 6) + (slot << 3);
  size_t dst = (size_t)row * K + (kb << 6) + (pslot << 3);
  u16x8 vh, vl;
#pragma unroll
  for (int i = 0; i < 8; ++i) {
    float f = src[i];
    _Float16 h = (_Float16)f;
    float hf = (float)h;
    if (fabsf(hf) < 6.103515625e-05f) { h = (_Float16)0.0f; hf = 0.0f; }
    float l = (f - hf) * 4096.0f;
    vh[i] = h2u(h);
    vl[i] = h2u((_Float16)l);
  }
  *reinterpret_cast<u16x8*>(oh + dst) = vh;
  *reinterpret_cast<u16x8*>(ol + dst) = vl;
}

// ---------------------------------------------------------------------------
// fp32 -> 3 bf16 exact split, mode-0 swizzle (L3 operands only).
// ---------------------------------------------------------------------------
__global__ __launch_bounds__(256) void split3_swz(
    const float* __restrict__ S, ushort* __restrict__ o1,
    ushort* __restrict__ o2, ushort* __restrict__ o3,
    int K, int nslots)
{
  int g = blockIdx.x * 256 + threadIdx.x;
  if (g >= nslots) return;
  int spr = K >> 3;
  int row = g / spr;
  int sl = g - row * spr;
  int kb = sl >> 3;
  int slot = sl & 7;
  int pslot = slot ^ (row & 7);
  const float* src = S + (size_t)row * K + (kb << 6) + (slot << 3);
  size_t dst = (size_t)row * K + (kb << 6) + (pslot << 3);
  u16x8 v1, v2, v3;
#pragma unroll
  for (int i = 0; i < 8; ++i) {
    float f = src[i];
    ushort h1 = f32_bf16_rne(f);
    float r = f - bf16_f32(h1);
    ushort h2 = f32_bf16_rne(r);
    float r2 = r - bf16_f32(h2);
    ushort h3 = f32_bf16_rne(r2);
    v1[i] = h1; v2[i] = h2; v3[i] = h3;
  }
  *reinterpret_cast<u16x8*>(o1 + dst) = v1;
  *reinterpret_cast<u16x8*>(o2 + dst) = v2;
  *reinterpret_cast<u16x8*>(o3 + dst) = v3;
}

// ---------------------------------------------------------------------------
// gemm_corr: L0 corr pass. A=xl, B=wh (NB=1). R13 gemm2<1,*> skeleton;
// epilogue WRITES curC = f16(accC) (runs first, no RMW).
// ---------------------------------------------------------------------------
__global__ __launch_bounds__(512) void gemm_corr(
    const ushort* __restrict__ A, const ushort* __restrict__ Bh,
    int NT, int K, int N, ushort* __restrict__ curC)
{
  __shared__ __align__(16) ushort lds[49152];  // 64KB A + 32KB B

  const int tid = threadIdx.x;
  const int lane = tid & 63;
  const int wid = tid >> 6;
  const int wm = wid >> 1;
  const int wn = wid & 1;
  const int lane15 = lane & 15;
  const int lhi = lane >> 4;
  const int sg2 = lhi ^ ((lane15 >> 1) & 3);

  int nwg = gridDim.x * gridDim.y;
  int bid = blockIdx.y * gridDim.x + blockIdx.x;
  int cpx = nwg >> 3;
  int sw = (bid & 7) * cpx + (bid >> 3);
  int bx = sw % gridDim.x, by = sw / gridDim.x;
  const int bm = by * 256, bn = bx * 128;

  const int sr2 = tid >> 2;
  const int sg = tid & 3;

  auto stage = [&](int t1, int h, int d) {
    const int k0 = t1 * 64 + h * 32;
#pragma unroll
    for (int l = 0; l < 2; ++l) {
      int row = sr2 + l * 128;
      __builtin_amdgcn_global_load_lds(
          (const __attribute__((address_space(1))) void*)(A + (size_t)(bm + row) * K + k0 + sg * 8),
          (__attribute__((address_space(3))) void*)(lds + d * 16384 + h * 8192 + row * 32 + sg * 8),
          16, 0, 0);
    }
    __builtin_amdgcn_global_load_lds(
        (const __attribute__((address_space(1))) void*)(Bh + (size_t)(bn + sr2) * K + k0 + sg * 8),
        (__attribute__((address_space(3))) void*)(lds + 32768 + (d * 2 + h) * 4096 + sr2 * 32 + sg * 8),
        16, 0, 0);
  };

  f32x4 accC[4][4];
#pragma unroll
  for (int i = 0; i < 4; ++i)
#pragma unroll
    for (int j = 0; j < 4; ++j)
      accC[i][j] = (f32x4){0.f, 0.f, 0.f, 0.f};

  stage(0, 0, 0);
  stage(0, 1, 0);
  asm volatile("s_waitcnt vmcnt(3)" ::: "memory");
  asm volatile("s_barrier" ::: "memory");

  for (int t = 0; t < NT; ++t) {
    const int d = t & 1;
#pragma unroll
    for (int h = 0; h < 2; ++h) {
      f16x8 af[4];
      const ushort* Ab = lds + (d * 2 + h) * 8192;
#pragma unroll
      for (int i = 0; i < 4; ++i)
        af[i] = *(const f16x8*)(Ab + (wm * 64 + i * 16 + lane15) * 32 + sg2 * 8);

      if (t < NT - 1) {
        stage(t + 1, h, d ^ 1);
        asm volatile("s_waitcnt vmcnt(3)" ::: "memory");
      } else if (h == 0) {
        asm volatile("s_waitcnt vmcnt(0)" ::: "memory");
      }
      asm volatile("s_barrier" ::: "memory");

      const ushort* Bb = lds + 32768 + (d * 2 + h) * 4096;
      f16x8 bf[4];
#pragma unroll
      for (int j = 0; j < 4; ++j)
        bf[j] = *(const f16x8*)(Bb + (wn * 64 + j * 16 + lane15) * 32 + sg2 * 8);
      __builtin_amdgcn_s_setprio(1);
#pragma unroll
      for (int i = 0; i < 4; ++i)
#pragma unroll
        for (int j = 0; j < 4; ++j)
          accC[i][j] = __builtin_amdgcn_mfma_f32_16x16x32_f16(af[i], bf[j], accC[i][j], 0, 0, 0);
      __builtin_amdgcn_s_setprio(0);
      asm volatile("s_barrier" ::: "memory");
    }
  }

#pragma unroll
  for (int i = 0; i < 4; ++i) {
    int r0 = bm + wm * 64 + i * 16 + lhi * 4;
#pragma unroll
    for (int j = 0; j < 4; ++j) {
      int col = bn + wn * 64 + j * 16 + lane15;
      f32x4 vc = accC[i][j];
#pragma unroll
      for (int r = 0; r < 4; ++r)
        curC[(size_t)(r0 + r) * N + col] = h2u((_Float16)vc[r]);
    }
  }
}

// ---------------------------------------------------------------------------
// gemm_mainL<HASC, FMT>: R13 gemm2<2,0> K-loop verbatim + fused LIF epilogue.
// A=xh/spikes; B segs {wh->accM, wl->accC}. Epilogue: corr = accC (+curC if
// HASC); cur = fma(corr, 2^-12, accM); tile -> LDS [256][132] f32;
// 512-thread scan (4 batches x 128 cols); swizzled spike store.
// FMT 1: f16 {0,0x3C00} mode-1 layout. FMT 0: bf16 {0,0x3F80} mode-0.
// ---------------------------------------------------------------------------
template<int HASC, int FMT>
__global__ __launch_bounds__(512) void gemm_mainL(
    const ushort* __restrict__ A,
    const ushort* __restrict__ Bh, const ushort* __restrict__ Bl,
    int NT, int K, int N,
    const ushort* __restrict__ curCin,
    const float* __restrict__ bias, ushort* __restrict__ spk)
{
  __shared__ __align__(16) ushort lds[67584];  // K-loop: 128KB; epilogue: [256][132] f32

  const int tid = threadIdx.x;
  const int lane = tid & 63;
  const int wid = tid >> 6;
  const int wm = wid >> 1;
  const int wn = wid & 1;
  const int lane15 = lane & 15;
  const int lhi = lane >> 4;
  const int sg2 = lhi ^ ((lane15 >> 1) & 3);

  int nwg = gridDim.x * gridDim.y;
  int bid = blockIdx.y * gridDim.x + blockIdx.x;
  int cpx = nwg >> 3;
  int sw = (bid & 7) * cpx + (bid >> 3);
  int bx = sw % gridDim.x, by = sw / gridDim.x;
  const int bm = by * 256, bn = bx * 128;

  const int sr2 = tid >> 2;
  const int sg = tid & 3;

  auto stage = [&](int t1, int h, int d) {
    const int k0 = t1 * 64 + h * 32;
#pragma unroll
    for (int l = 0; l < 2; ++l) {
      int row = sr2 + l * 128;
      __builtin_amdgcn_global_load_lds(
          (const __attribute__((address_space(1))) void*)(A + (size_t)(bm + row) * K + k0 + sg * 8),
          (__attribute__((address_space(3))) void*)(lds + d * 16384 + h * 8192 + row * 32 + sg * 8),
          16, 0, 0);
    }
#pragma unroll
    for (int s = 0; s < 2; ++s) {
      const ushort* Bp = (s == 0) ? Bh : Bl;
      __builtin_amdgcn_global_load_lds(
          (const __attribute__((address_space(1))) void*)(Bp + (size_t)(bn + sr2) * K + k0 + sg * 8),
          (__attribute__((address_space(3))) void*)(lds + 32768 + ((d * 2 + h) * 2 + s) * 4096 + sr2 * 32 + sg * 8),
          16, 0, 0);
    }
  };

  f32x4 accM[4][4], accC[4][4];
#pragma unroll
  for (int i = 0; i < 4; ++i)
#pragma unroll
    for (int j = 0; j < 4; ++j) {
      accM[i][j] = (f32x4){0.f, 0.f, 0.f, 0.f};
      accC[i][j] = (f32x4){0.f, 0.f, 0.f, 0.f};
    }

  stage(0, 0, 0);
  stage(0, 1, 0);
  asm volatile("s_waitcnt vmcnt(4)" ::: "memory");
  asm volatile("s_barrier" ::: "memory");

  for (int t = 0; t < NT; ++t) {
    const int d = t & 1;
#pragma unroll
    for (int h = 0; h < 2; ++h) {
      f16x8 af[4];
      const ushort* Ab = lds + (d * 2 + h) * 8192;
#pragma unroll
      for (int i = 0; i < 4; ++i)
        af[i] = *(const f16x8*)(Ab + (wm * 64 + i * 16 + lane15) * 32 + sg2 * 8);

      if (t < NT - 1) {
        stage(t + 1, h, d ^ 1);
        asm volatile("s_waitcnt vmcnt(4)" ::: "memory");
      } else if (h == 0) {
        asm volatile("s_waitcnt vmcnt(0)" ::: "memory");
      }
      asm volatile("s_barrier" ::: "memory");

      __builtin_amdgcn_s_setprio(1);
#pragma unroll
      for (int s = 0; s < 2; ++s) {
        const ushort* Bb = lds + 32768 + ((d * 2 + h) * 2 + s) * 4096;
        f16x8 bf[4];
#pragma unroll
        for (int j = 0; j < 4; ++j)
          bf[j] = *(const f16x8*)(Bb + (wn * 64 + j * 16 + lane15) * 32 + sg2 * 8);
        if (s == 0) {
#pragma unroll
          for (int i = 0; i < 4; ++i)
#pragma unroll
            for (int j = 0; j < 4; ++j)
              accM[i][j] = __builtin_amdgcn_mfma_f32_16x16x32_f16(af[i], bf[j], accM[i][j], 0, 0, 0);
        } else {
#pragma unroll
          for (int i = 0; i < 4; ++i)
#pragma unroll
            for (int j = 0; j < 4; ++j)
              accC[i][j] = __builtin_amdgcn_mfma_f32_16x16x32_f16(af[i], bf[j], accC[i][j], 0, 0, 0);
        }
      }
      __builtin_amdgcn_s_setprio(0);
      asm volatile("s_barrier" ::: "memory");
    }
  }

  // ---- fused LIF epilogue ----
  float* curb = (float*)lds;       // [256][132] f32 = 135168 B
#pragma unroll
  for (int i = 0; i < 4; ++i) {
    int rl = wm * 64 + i * 16 + lhi * 4;
#pragma unroll
    for (int j = 0; j < 4; ++j) {
      int cl = wn * 64 + j * 16 + lane15;
      f32x4 vm = accM[i][j], vc = accC[i][j];
#pragma unroll
      for (int r = 0; r < 4; ++r) {
        float corr = vc[r];
        if (HASC)
          corr += (float)u2h(curCin[(size_t)(bm + rl + r) * N + (bn + cl)]);
        curb[(rl + r) * 132 + cl] = __fmaf_rn(corr, 2.44140625e-4f, vm[r]);
      }
    }
  }
  __syncthreads();

  {
    int b2 = tid >> 7;           // 0..3 (batch within tile)
    int n = tid & 127;
    int cg = bn + n;
    float bv = bias[cg];
    int nb6 = cg >> 6;
    int sl = (cg >> 3) & 7;
    int nlow = cg & 7;
    const ushort one = FMT ? (ushort)0x3C00 : (ushort)0x3F80;
    float mem = 0.f;
    for (int t2 = 0; t2 < 64; ++t2) {
      float c = __fadd_rn(curb[(b2 * 64 + t2) * 132 + n], bv);
      float reset = ((mem - 1.0f) > 0.0f) ? 1.0f : 0.0f;
      mem = __fmul_rn(BETA, mem);
      mem = __fadd_rn(mem, c);
      mem = __fadd_rn(mem, -reset);
      ushort sv = ((mem - 1.0f) > 0.0f) ? one : (ushort)0;
      int m = bm + b2 * 64 + t2;
      int ps = FMT ? ((sl & 4) | ((sl & 3) ^ ((m >> 1) & 3)))
                   : (sl ^ (m & 7));
      spk[(size_t)m * N + (nb6 << 6) + (ps << 3) + nlow] = sv;
    }
  }
}

// ---------------------------------------------------------------------------
// gemm_seg_lif (L3): 128x128 tile, K=1024, N=128, bf16 mode-0 3-split.
// Dual acc: p0 (w3s[0]) -> accM; p1,p2 (w3s[1],w3s[2]) chained -> accC
// (identical arithmetic order to R13's two launches). Fused LIF writes
// spk3/mem3 (fp32) directly.
// ---------------------------------------------------------------------------
__global__ __launch_bounds__(256) void gemm_seg_lif(
    const ushort* __restrict__ A0,
    const ushort* __restrict__ B0, const ushort* __restrict__ B1,
    const ushort* __restrict__ B2,
    const float* __restrict__ bias,
    float* __restrict__ spk_out, float* __restrict__ mem_out)
{
  __shared__ ushort As[128 * 64];
  __shared__ ushort Bs[128 * 64];
  __shared__ float curb[128 * 132];

  const int tid = threadIdx.x;
  const int lane = tid & 63;
  const int wid = tid >> 6;
  const int wr = wid >> 1, wc = wid & 1;
  const int lane15 = lane & 15;
  const int lhi = lane >> 4;
  const int rswz = lane15 & 7;
  const int lrow = lane >> 3, lslot = lane & 7;

  int nwg = gridDim.x * gridDim.y;
  int bid = blockIdx.y * gridDim.x + blockIdx.x;
  int cpx = nwg >> 3;
  int sw = (bid & 7) * cpx + (bid >> 3);
  int bx = sw % gridDim.x, by = sw / gridDim.x;
  const int bm = by * 128, bn = bx * 128;

  f32x4 accM[4][4], accC[4][4];
#pragma unroll
  for (int i = 0; i < 4; ++i)
#pragma unroll
    for (int j = 0; j < 4; ++j) {
      accM[i][j] = (f32x4){0.f, 0.f, 0.f, 0.f};
      accC[i][j] = (f32x4){0.f, 0.f, 0.f, 0.f};
    }

  const bool isA = (wid < 2);
  ushort* lbase = isA ? As : Bs;
  const int rowbase0 = isA ? bm : bn;
  const int chunk0 = (wid & 1) * 8;

  for (int p = 0; p < 3; ++p) {
    const ushort* Bp = (p == 0) ? B0 : ((p == 1) ? B1 : B2);
    const ushort* gsrc = isA ? A0 : Bp;
    for (int k0 = 0; k0 < 1024; k0 += 64) {
      __syncthreads();
#pragma unroll
      for (int c = 0; c < 8; ++c) {
        int chunk = chunk0 + c;
        int row = chunk * 8 + lrow;
        const ushort* g = gsrc + (size_t)(rowbase0 + row) * 1024 + k0 + (lslot << 3);
        __builtin_amdgcn_global_load_lds(
            (const __attribute__((address_space(1))) void*)(g),
            (__attribute__((address_space(3))) void*)(lbase + chunk * 512),
            16, 0, 0);
      }
      __syncthreads();
#pragma unroll
      for (int kk = 0; kk < 2; ++kk) {
        int sp = ((kk << 2) | lhi) ^ rswz;
        bf16x8 af[4], bg[4];
#pragma unroll
        for (int i = 0; i < 4; ++i)
          af[i] = *(const bf16x8*)(As + (wr * 64 + i * 16 + lane15) * 64 + sp * 8);
#pragma unroll
        for (int j = 0; j < 4; ++j)
          bg[j] = *(const bf16x8*)(Bs + (wc * 64 + j * 16 + lane15) * 64 + sp * 8);
        if (p == 0) {
#pragma unroll
          for (int i = 0; i < 4; ++i)
#pragma unroll
            for (int j = 0; j < 4; ++j)
              accM[i][j] = __builtin_amdgcn_mfma_f32_16x16x32_bf16(af[i], bg[j], accM[i][j], 0, 0, 0);
        } else {
#pragma unroll
          for (int i = 0; i < 4; ++i)
#pragma unroll
            for (int j = 0; j < 4; ++j)
              accC[i][j] = __builtin_amdgcn_mfma_f32_16x16x32_bf16(af[i], bg[j], accC[i][j], 0, 0, 0);
        }
      }
    }
  }

  // cur = accM + accC (single add, matches R13's RMW) -> LDS; LIF scan.
  __syncthreads();
#pragma unroll
  for (int j = 0; j < 4; ++j) {
    int cl = wc * 64 + j * 16 + lane15;
#pragma unroll
    for (int i = 0; i < 4; ++i) {
      int rl = wr * 64 + i * 16 + lhi * 4;
      f32x4 vm = accM[i][j], vc = accC[i][j];
#pragma unroll
      for (int r = 0; r < 4; ++r)
        curb[(rl + r) * 132 + cl] = vm[r] + vc[r];
    }
  }
  __syncthreads();

  {
    int b2 = tid >> 7;           // 0..1
    int n = tid & 127;
    float bv = bias[bn + n];
    float mem = 0.f;
    for (int t2 = 0; t2 < 64; ++t2) {
      float c = __fadd_rn(curb[(b2 * 64 + t2) * 132 + n], bv);
      float reset = ((mem - 1.0f) > 0.0f) ? 1.0f : 0.0f;
      mem = __fmul_rn(BETA, mem);
      mem = __fadd_rn(mem, c);
      mem = __fadd_rn(mem, -reset);
      int m = bm + b2 * 64 + t2;
      size_t idx = (size_t)m * 128 + bn + n;
      spk_out[idx] = ((mem - 1.0f) > 0.0f) ? 1.0f : 0.0f;
      mem_out[idx] = mem;
    }
  }
}

extern "C" void kernel_launch(void* const* d_in, const int* in_sizes, int n_in,
                              void* d_out, int out_size, void* d_ws, size_t ws_size,
                              hipStream_t stream)
{
  const float* x  = (const float*)d_in[0];
  const float* W0 = (const float*)d_in[1];
  const float* b0 = (const float*)d_in[2];
  const float* W1 = (const float*)d_in[3];
  const float* b1 = (const float*)d_in[4];
  const float* W2 = (const float*)d_in[5];
  const float* b2 = (const float*)d_in[6];
  const float* W3 = (const float*)d_in[7];
  const float* b3 = (const float*)d_in[8];
  float* out = (float*)d_out;

  char* ws = (char*)d_ws;
  size_t off = 0;
  auto take = [&](size_t bytes) -> char* {
    char* p = ws + off;
    off += (bytes + 255) & ~(size_t)255;
    return p;
  };

  ushort* w0h = (ushort*)take((size_t)2048 * 2048 * 2);
  ushort* w0l = (ushort*)take((size_t)2048 * 2048 * 2);
  ushort* w1h = (ushort*)take((size_t)2048 * 2048 * 2);
  ushort* w1l = (ushort*)take((size_t)2048 * 2048 * 2);
  ushort* w2h = (ushort*)take((size_t)1024 * 2048 * 2);
  ushort* w2l = (ushort*)take((size_t)1024 * 2048 * 2);
  ushort* w3s[3];
  for (int i = 0; i < 3; ++i) w3s[i] = (ushort*)take((size_t)128 * 1024 * 2);
  ushort* xh = (ushort*)take((size_t)M_ * 2048 * 2);
  ushort* xl = (ushort*)take((size_t)M_ * 2048 * 2);
  ushort* s0 = (ushort*)take((size_t)M_ * 2048 * 2);
  ushort* curC = (ushort*)take((size_t)M_ * 2048 * 2);
  // s1 aliases xh (dead after L0 main), s2 aliases xl (dead after gemm_corr)
  ushort* s1 = xh;
  ushort* s2 = xl;

  dim3 blk(256);
  dim3 fblk(512);

  // --- splits ---
  {
    int ns = 2048 * 2048 / 8;
    split2_f16<<<(ns + 255) / 256, blk, 0, stream>>>(W0, w0h, w0l, 2048, ns);
    split2_f16<<<(ns + 255) / 256, blk, 0, stream>>>(W1, w1h, w1l, 2048, ns);
    ns = 1024 * 2048 / 8;
    split2_f16<<<(ns + 255) / 256, blk, 0, stream>>>(W2, w2h, w2l, 2048, ns);
    ns = 128 * 1024 / 8;
    split3_swz<<<(ns + 255) / 256, blk, 0, stream>>>(W3, w3s[0], w3s[1], w3s[2], 1024, ns);
    ns = M_ * 2048 / 8;
    split2_f16<<<(ns + 255) / 256, blk, 0, stream>>>(x, xh, xl, 2048, ns);
  }

  // --- L0: corr first (xl*wh -> curC), then main (xh*{wh,wl}) + LIF -> s0 ---
  {
    dim3 grid(2048 / 128, M_ / 256);   // (16, 32)
    gemm_corr<<<grid, fblk, 0, stream>>>(xl, w0h, 32, 2048, 2048, curC);
    gemm_mainL<1, 1><<<grid, fblk, 0, stream>>>(xh, w0h, w0l, 32, 2048, 2048, curC, b0, s0);
  }
  // --- L1 ---
  {
    dim3 grid(2048 / 128, M_ / 256);
    gemm_mainL<0, 1><<<grid, fblk, 0, stream>>>(s0, w1h, w1l, 32, 2048, 2048, nullptr, b1, s1);
  }
  // --- L2 (spikes out bf16 mode-0 for L3) ---
  {
    dim3 grid(1024 / 128, M_ / 256);   // (8, 32)
    gemm_mainL<0, 0><<<grid, fblk, 0, stream>>>(s1, w2h, w2l, 32, 2048, 1024, nullptr, b2, s2);
  }
  // --- L3: single fused kernel -> spk3, mem3 ---
  {
    float* spk3 = out;
    float* mem3 = out + (size_t)M_ * NOUT;
    gemm_seg_lif<<<dim3(1, 64), blk, 0, stream>>>(s2, w3s[0], w3s[1], w3s[2], b3, spk3, mem3);
  }
}